// Round 8
// baseline (1079.754 us; speedup 1.0000x reference)
//
#include <hip/hip_runtime.h>
#include <hip/hip_bf16.h>

#define K_TOT 4096
#define N_TOT 11008
#define LDP 72

typedef __bf16 bf16x8 __attribute__((ext_vector_type(8)));
typedef float  f32x4  __attribute__((ext_vector_type(4)));
typedef float  f32x8  __attribute__((ext_vector_type(8)));

typedef __attribute__((address_space(1))) unsigned gu32;
typedef __attribute__((address_space(3))) unsigned lu32;

__device__ __forceinline__ void gload_lds16(const void* g, void* l) {
    __builtin_amdgcn_global_load_lds((gu32*)g, (lu32*)l, 16, 0, 0);
}

// ---------- prepass 1: dequant packed int4 -> bf16 W[N][K] ----------
__global__ __launch_bounds__(256)
void dequant_w(const int* __restrict__ Qw, const float* __restrict__ Sc,
               const float* __restrict__ Zr, __bf16* __restrict__ Wb)
{
    const int t   = blockIdx.x * 256 + threadIdx.x;
    const int c8  = t & (K_TOT / 8 - 1);
    const int r4  = t >> 9;
    const int kp0 = c8 * 8;
    const int n   = r4 * 4 + ((kp0 >> 4) & 3);
    const int kq  = kp0 >> 6;
    const int hf  = (kp0 >> 3) & 1;
    const int kb  = kq * 64 + hf * 32;

    const int4 wa = *(const int4*)(Qw + (size_t)r4 * K_TOT + kp0);
    const int4 wb = *(const int4*)(Qw + (size_t)r4 * K_TOT + kp0 + 4);
    const int g = kb >> 7;
    const float s = Sc[(size_t)g * N_TOT + n];
    const float z = Zr[(size_t)g * N_TOT + n];

    const int w8[8] = {wa.x, wa.y, wa.z, wa.w, wb.x, wb.y, wb.z, wb.w};
    bf16x8 ov[4];
    #pragma unroll
    for (int uu = 0; uu < 8; ++uu) {
        const unsigned v = (unsigned)w8[uu] & 0xFFFFu;
        #pragma unroll
        for (int i = 0; i < 4; ++i)
            ov[i][uu] = (__bf16)fmaf((float)((v >> (4 * i)) & 0xFu), s, z);
    }
    __bf16* o = Wb + (size_t)n * K_TOT + kb;
    #pragma unroll
    for (int i = 0; i < 4; ++i) *(bf16x8*)(o + i * 8) = ov[i];
}

// ---------- prepass 2: X f32 -> bf16 ----------
__global__ __launch_bounds__(256)
void convert_x(const float* __restrict__ X, __bf16* __restrict__ Xb, long total8)
{
    const long t = (long)blockIdx.x * 256 + threadIdx.x;
    if (t >= total8) return;
    f32x8 v = *(const f32x8*)(X + t * 8);
    bf16x8 o;
    #pragma unroll
    for (int j = 0; j < 8; ++j) o[j] = (__bf16)v[j];
    *(bf16x8*)(Xb + t * 8) = o;
}

// ---------- main: 256x128 tile, 8 waves of 64x64, 3-deep LDS ring,
// fine-interleaved 2-phase schedule (m196/m201 phase shape), vmcnt(6) gate ----------
#define STAGE_A(kt, r, dst) \
    gload_lds16(apg + (size_t)(r) * 64 * K_TOT + (size_t)(kt) * 64, (dst) + wid * 1024 + (r) * 8192)
#define STAGE_B(kt, r, dst) \
    gload_lds16(bpg + (size_t)(r) * 64 * K_TOT + (size_t)(kt) * 64, (dst) + 32768 + wid * 1024 + (r) * 8192)

__global__ __launch_bounds__(512, 1)
void gemm256x128(const __bf16* __restrict__ A, const __bf16* __restrict__ B,
                 const float* __restrict__ Bias, float* __restrict__ C, int gridM)
{
    extern __shared__ char lds_raw[];   // 3 slots x (A 32K | B 16K) = 147456 B

    const int tid  = threadIdx.x;
    const int lane = tid & 63;
    const int wid  = tid >> 6;          // 0..7
    const int l15  = lane & 15;
    const int lhi  = lane >> 4;

    // T1: bijective XCD swizzle (nwg % 8 == 0 guaranteed by host guard)
    const int nwg = gridDim.x;
    int wg = blockIdx.x;
    wg = (wg & 7) * (nwg >> 3) + (wg >> 3);
    const int bx  = wg % gridM;
    const int by  = wg / gridM;
    const int bm0 = bx * 256;
    const int bn0 = by * 128;

    const int wm = (wid >> 1) * 64;     // 0/64/128/192
    const int wn = (wid & 1) * 64;      // 0/64

    // staging source (pre-swizzled col so linear LDS dest == swizzled layout)
    const int sr   = lane >> 3;
    const int scol = ((lane & 7) ^ sr) * 8;
    const __bf16* apg = A + (size_t)(bm0 + wid * 8 + sr) * K_TOT + scol;
    const __bf16* bpg = B + (size_t)(bn0 + wid * 8 + sr) * K_TOT + scol;

    char* s0 = lds_raw;                 // tile t
    char* s1 = lds_raw + 49152;         // tile t+1
    char* s2 = lds_raw + 98304;         // stage target (tile t+2)

    const unsigned rswz = (unsigned)((l15 & 7) << 4);

    f32x4 acc[4][4] = {};

    // prologue: stage tile 0 -> s0, tile 1 -> s1 (6 loads each)
    STAGE_A(0, 0, s0); STAGE_A(0, 1, s0); STAGE_A(0, 2, s0); STAGE_A(0, 3, s0);
    STAGE_B(0, 0, s0); STAGE_B(0, 1, s0);
    STAGE_A(1, 0, s1); STAGE_A(1, 1, s1); STAGE_A(1, 2, s1); STAGE_A(1, 3, s1);
    STAGE_B(1, 0, s1); STAGE_B(1, 1, s1);
    asm volatile("s_waitcnt vmcnt(6)" ::: "memory");   // tile 0 landed; tile 1 afloat
    __builtin_amdgcn_s_barrier();

    const int NT = K_TOT / 64;          // 64
    for (int t = 0; t < NT; ++t) {
        const int kt2 = (t + 2 < NT) ? t + 2 : NT - 1;   // clamped re-stage at tail

        bf16x8 a8[4][2], bq0[2][2], bq1[2][2];

        // ---- phase 0: reads (A all, B nq0) | stage 3 | barrier | MFMA nq0 ----
        #pragma unroll
        for (int kk = 0; kk < 2; ++kk) {
            const unsigned cb = ((unsigned)(kk * 64 + lhi * 16)) ^ rswz;
            #pragma unroll
            for (int mi = 0; mi < 4; ++mi)
                a8[mi][kk] = *(const bf16x8*)(s0 + (wm + mi * 16 + l15) * 128 + cb);
            #pragma unroll
            for (int nj = 0; nj < 2; ++nj)
                bq0[nj][kk] = *(const bf16x8*)(s0 + 32768 + (wn + nj * 16 + l15) * 128 + cb);
        }
        STAGE_A(kt2, 0, s2); STAGE_A(kt2, 1, s2); STAGE_A(kt2, 2, s2);
        asm volatile("s_waitcnt lgkmcnt(8)" ::: "memory");
        __builtin_amdgcn_s_barrier();
        asm volatile("s_waitcnt lgkmcnt(0)" ::: "memory");
        __builtin_amdgcn_sched_barrier(0);
        __builtin_amdgcn_s_setprio(1);
        #pragma unroll
        for (int mi = 0; mi < 4; ++mi)
            #pragma unroll
            for (int nj = 0; nj < 2; ++nj)
                #pragma unroll
                for (int kk = 0; kk < 2; ++kk)
                    acc[mi][nj] = __builtin_amdgcn_mfma_f32_16x16x32_bf16(
                        a8[mi][kk], bq0[nj][kk], acc[mi][nj], 0, 0, 0);
        __builtin_amdgcn_s_setprio(0);
        __builtin_amdgcn_s_barrier();

        // ---- phase 1: reads (B nq1) | stage 3 | vmcnt(6) | barrier | MFMA nq1 ----
        #pragma unroll
        for (int kk = 0; kk < 2; ++kk) {
            const unsigned cb = ((unsigned)(kk * 64 + lhi * 16)) ^ rswz;
            #pragma unroll
            for (int nj = 0; nj < 2; ++nj)
                bq1[nj][kk] = *(const bf16x8*)(s0 + 32768 + (wn + 32 + nj * 16 + l15) * 128 + cb);
        }
        STAGE_A(kt2, 3, s2); STAGE_B(kt2, 0, s2); STAGE_B(kt2, 1, s2);
        asm volatile("s_waitcnt vmcnt(6)" ::: "memory");   // gate tile t+1; t+2 stays afloat
        __builtin_amdgcn_s_barrier();
        asm volatile("s_waitcnt lgkmcnt(0)" ::: "memory");
        __builtin_amdgcn_sched_barrier(0);
        __builtin_amdgcn_s_setprio(1);
        #pragma unroll
        for (int mi = 0; mi < 4; ++mi)
            #pragma unroll
            for (int nj = 0; nj < 2; ++nj)
                #pragma unroll
                for (int kk = 0; kk < 2; ++kk)
                    acc[mi][2 + nj] = __builtin_amdgcn_mfma_f32_16x16x32_bf16(
                        a8[mi][kk], bq1[nj][kk], acc[mi][2 + nj], 0, 0, 0);
        __builtin_amdgcn_s_setprio(0);
        __builtin_amdgcn_s_barrier();

        char* tmp = s0; s0 = s1; s1 = s2; s2 = tmp;   // ring rotate
    }

    // epilogue: C/D layout col=lane&15, row=(lane>>4)*4+reg
    #pragma unroll
    for (int ni = 0; ni < 4; ++ni) {
        const int col = bn0 + wn + ni * 16 + l15;
        const float bv = Bias[col];
        #pragma unroll
        for (int mi = 0; mi < 4; ++mi) {
            const int row = bm0 + wm + mi * 16 + lhi * 4;
            #pragma unroll
            for (int r = 0; r < 4; ++r)
                C[(size_t)(row + r) * N_TOT + col] = acc[mi][ni][r] + bv;
        }
    }
}

// ---------- fallback: round-3 fused kernel ----------
__global__ __launch_bounds__(256)
void qgemm_fused(const float* __restrict__ X, const int* __restrict__ Qw,
                 const float* __restrict__ Sc, const float* __restrict__ Zr,
                 const float* __restrict__ Bias, float* __restrict__ C)
{
    __shared__ __bf16 As[128][LDP];
    __shared__ __bf16 Bs[128][LDP];

    const int tid  = threadIdx.x;
    const int lane = tid & 63;
    const int wid  = tid >> 6;
    const int l15  = lane & 15;
    const int lhi  = lane >> 4;

    const int bm0 = blockIdx.x * 128;
    const int bn0 = blockIdx.y * 128;
    const int wm  = (wid >> 1) * 64;
    const int wn  = (wid & 1) * 64;

    const int ar = tid >> 3;
    const int ac = (tid & 7) * 8;

    const int nl   = tid >> 1;
    const int half = tid & 1;
    const int n_g  = bn0 + nl;
    const int* qptr = Qw + (size_t)(n_g >> 2) * K_TOT + (nl & 3) * 16 + half * 8;
    const float* scp = Sc + n_g;
    const float* zrp = Zr + n_g;

    f32x4 acc[4][4] = {};

    for (int kt = 0; kt < K_TOT / 64; ++kt) {
        const int k0 = kt * 64;
        const int4 wa = *(const int4*)(qptr + k0);
        const int4 wb = *(const int4*)(qptr + k0 + 4);
        const float s = scp[(size_t)(kt >> 1) * N_TOT];
        const float z = zrp[(size_t)(kt >> 1) * N_TOT];

        f32x8 av[4];
        #pragma unroll
        for (int p = 0; p < 4; ++p)
            av[p] = *(const f32x8*)(X + (size_t)(bm0 + p * 32 + ar) * K_TOT + k0 + ac);

        const int w8[8] = {wa.x, wa.y, wa.z, wa.w, wb.x, wb.y, wb.z, wb.w};
        bf16x8 ov[4];
        #pragma unroll
        for (int uu = 0; uu < 8; ++uu) {
            const unsigned v = (unsigned)w8[uu] & 0xFFFFu;
            #pragma unroll
            for (int i = 0; i < 4; ++i)
                ov[i][uu] = (__bf16)fmaf((float)((v >> (4 * i)) & 0xFu), s, z);
        }
        #pragma unroll
        for (int p = 0; p < 4; ++p) {
            bf16x8 ab;
            #pragma unroll
            for (int j = 0; j < 8; ++j) ab[j] = (__bf16)av[p][j];
            *(bf16x8*)&As[p * 32 + ar][ac] = ab;
        }
        #pragma unroll
        for (int cc = 0; cc < 4; ++cc)
            *(bf16x8*)&Bs[nl][half * 32 + cc * 8] = ov[cc];

        __syncthreads();

        #pragma unroll
        for (int ks = 0; ks < 2; ++ks) {
            bf16x8 af[4], bfr[4];
            const int kc = ks * 32 + lhi * 8;
            #pragma unroll
            for (int mi = 0; mi < 4; ++mi)
                af[mi] = *(const bf16x8*)&As[wm + mi * 16 + l15][kc];
            #pragma unroll
            for (int ni = 0; ni < 4; ++ni)
                bfr[ni] = *(const bf16x8*)&Bs[wn + ni * 16 + l15][kc];
            #pragma unroll
            for (int mi = 0; mi < 4; ++mi)
                #pragma unroll
                for (int ni = 0; ni < 4; ++ni)
                    acc[mi][ni] = __builtin_amdgcn_mfma_f32_16x16x32_bf16(
                        af[mi], bfr[ni], acc[mi][ni], 0, 0, 0);
        }
        __syncthreads();
    }

    #pragma unroll
    for (int ni = 0; ni < 4; ++ni) {
        const int col = bn0 + wn + ni * 16 + l15;
        const float bv = Bias[col];
        #pragma unroll
        for (int mi = 0; mi < 4; ++mi) {
            const int row = bm0 + wm + mi * 16 + lhi * 4;
            #pragma unroll
            for (int r = 0; r < 4; ++r)
                C[(size_t)(row + r) * N_TOT + col] = acc[mi][ni][r] + bv;
        }
    }
}

extern "C" void kernel_launch(void* const* d_in, const int* in_sizes, int n_in,
                              void* d_out, int out_size, void* d_ws, size_t ws_size,
                              hipStream_t stream) {
    const float* X    = (const float*)d_in[0];
    const int*   Qw   = (const int*)d_in[1];
    const float* Sc   = (const float*)d_in[2];
    const float* Zr   = (const float*)d_in[3];
    const float* Bias = (const float*)d_in[4];
    float* C = (float*)d_out;

    const int M = in_sizes[0] / K_TOT;                 // 8192
    const size_t xb_bytes = (size_t)M * K_TOT * 2;
    const size_t wb_bytes = (size_t)N_TOT * K_TOT * 2;
    const size_t need = xb_bytes + wb_bytes;

    const int gridM = M / 256;
    const int nwg   = gridM * (N_TOT / 128);           // 32*86 = 2752

    if (ws_size >= need && (M & 255) == 0 && (nwg & 7) == 0) {
        __bf16* Xb = (__bf16*)d_ws;
        __bf16* Wb = (__bf16*)((char*)d_ws + xb_bytes);

        const int nW = (N_TOT / 4) * (K_TOT / 8);
        dequant_w<<<nW / 256, 256, 0, stream>>>(Qw, Sc, Zr, Wb);

        const long total8 = (long)M * K_TOT / 8;
        convert_x<<<(int)((total8 + 255) / 256), 256, 0, stream>>>(X, Xb, total8);

        (void)hipFuncSetAttribute((const void*)gemm256x128,
                                  hipFuncAttributeMaxDynamicSharedMemorySize, 147456);
        gemm256x128<<<dim3(nwg), dim3(512), 147456, stream>>>(Xb, Wb, Bias, C, gridM);
    } else {
        dim3 grid(M / 128, N_TOT / 128);
        qgemm_fused<<<grid, dim3(256), 0, stream>>>(X, Qw, Sc, Zr, Bias, C);
    }
}